// Round 2
// baseline (518.862 us; speedup 1.0000x reference)
//
#include <hip/hip_runtime.h>
#include <cstddef>

#define N_NODES 8192
#define F_IN    512
#define HID     256
#define EMB     64
#define NEDGE   262144
#define NT      (N_NODES / 128)   // 64 decode tiles per dim

// ---------------- CSR build ----------------

__global__ __launch_bounds__(256) void k_zero(int* __restrict__ p, int n) {
    int i = blockIdx.x * 256 + threadIdx.x;
    if (i < n) p[i] = 0;
}

__global__ __launch_bounds__(256) void k_count(const int* __restrict__ src, int* __restrict__ cnt) {
    int e = blockIdx.x * 256 + threadIdx.x;
    if (e < NEDGE) atomicAdd(&cnt[src[e]], 1);
}

// single block, 1024 threads, scans 8192 counts -> exclusive offsets + cursor copy
__global__ __launch_bounds__(1024) void k_scan(int* __restrict__ cnt_cursor, int* __restrict__ offs) {
    __shared__ int part[1024];
    const int t = threadIdx.x;
    int v[8];
    int s = 0;
#pragma unroll
    for (int i = 0; i < 8; i++) { v[i] = cnt_cursor[t * 8 + i]; s += v[i]; }
    part[t] = s;
    __syncthreads();
    for (int off = 1; off < 1024; off <<= 1) {
        int x = (t >= off) ? part[t - off] : 0;
        __syncthreads();
        part[t] += x;
        __syncthreads();
    }
    int run = part[t] - s;  // exclusive prefix of this thread's chunk
#pragma unroll
    for (int i = 0; i < 8; i++) {
        offs[t * 8 + i] = run;
        cnt_cursor[t * 8 + i] = run;  // cursor for fill
        run += v[i];
    }
    if (t == 1023) offs[8192] = run;  // == NEDGE
}

__global__ __launch_bounds__(256) void k_fill(const int* __restrict__ src, const int* __restrict__ dst,
                                              const float* __restrict__ w, int* __restrict__ cursor,
                                              int* __restrict__ edst, float* __restrict__ ewl) {
    int e = blockIdx.x * 256 + threadIdx.x;
    if (e < NEDGE) {
        int p = atomicAdd(&cursor[src[e]], 1);
        edst[p] = dst[e];
        ewl[p]  = w[e];
    }
}

// ---------------- fp32 tiled GEMM: C[M,N] = A[M,K] @ B[K,N] ----------------
// threads = (BM/TM)*(BN/TN) == 256; M%BM==0, N%BN==0, K%BK==0; BK%4==0.

template <int BM, int BN, int BK, int TM, int TN>
__global__ __launch_bounds__(256) void gemm_f32(const float* __restrict__ A, const float* __restrict__ B,
                                                float* __restrict__ C, int M, int N, int K) {
    __shared__ float As[BK][BM];  // A stored transposed
    __shared__ float Bs[BK][BN];
    const int tid = threadIdx.x;
    const int tx = tid % (BN / TN);
    const int ty = tid / (BN / TN);
    const int m0 = blockIdx.y * BM, n0 = blockIdx.x * BN;

    float acc[TM][TN];
#pragma unroll
    for (int i = 0; i < TM; i++)
#pragma unroll
        for (int j = 0; j < TN; j++) acc[i][j] = 0.f;

    for (int kt = 0; kt < K; kt += BK) {
        // A tile: BM*BK elems, float4 per thread-iter, store transposed
        for (int idx = tid * 4; idx < BM * BK; idx += 256 * 4) {
            int r = idx / BK, c = idx % BK;
            float4 v = *(const float4*)&A[(size_t)(m0 + r) * K + kt + c];
            As[c + 0][r] = v.x; As[c + 1][r] = v.y; As[c + 2][r] = v.z; As[c + 3][r] = v.w;
        }
        // B tile: BK*BN elems, direct float4
        for (int idx = tid * 4; idx < BK * BN; idx += 256 * 4) {
            int r = idx / BN, c = idx % BN;
            *(float4*)&Bs[r][c] = *(const float4*)&B[(size_t)(kt + r) * N + n0 + c];
        }
        __syncthreads();
#pragma unroll
        for (int k = 0; k < BK; k++) {
            float a[TM], b[TN];
            if constexpr (TM == 4) {
                float4 va = *(const float4*)&As[k][ty * TM];
                a[0] = va.x; a[1] = va.y; a[2] = va.z; a[3] = va.w;
            } else {
                float2 va = *(const float2*)&As[k][ty * TM];
                a[0] = va.x; a[1] = va.y;
            }
            if constexpr (TN == 4) {
                float4 vb = *(const float4*)&Bs[k][tx * TN];
                b[0] = vb.x; b[1] = vb.y; b[2] = vb.z; b[3] = vb.w;
            } else {
                float2 vb = *(const float2*)&Bs[k][tx * TN];
                b[0] = vb.x; b[1] = vb.y;
            }
#pragma unroll
            for (int i = 0; i < TM; i++)
#pragma unroll
                for (int j = 0; j < TN; j++) acc[i][j] += a[i] * b[j];
        }
        __syncthreads();
    }
#pragma unroll
    for (int i = 0; i < TM; i++) {
        size_t row = (size_t)(m0 + ty * TM + i);
#pragma unroll
        for (int j = 0; j < TN; j++) C[row * N + n0 + tx * TN + j] = acc[i][j];
    }
}

// ---------------- SpMM: out[n] = sum_e w_e * sup[dst_e], CSR row gather ----------------

template <int F>
__global__ __launch_bounds__(F) void spmm_f32(const float* __restrict__ sup, const int* __restrict__ offs,
                                              const int* __restrict__ edst, const float* __restrict__ ewl,
                                              float* __restrict__ out) {
    const int n = blockIdx.x;
    const int f = threadIdx.x;
    const int s = offs[n], e = offs[n + 1];
    float acc = 0.f;
    int i = s;
    for (; i + 4 <= e; i += 4) {
        int   d0 = edst[i],     d1 = edst[i + 1], d2 = edst[i + 2], d3 = edst[i + 3];
        float w0 = ewl[i],      w1 = ewl[i + 1],  w2 = ewl[i + 2],  w3 = ewl[i + 3];
        acc += w0 * sup[(size_t)d0 * F + f];
        acc += w1 * sup[(size_t)d1 * F + f];
        acc += w2 * sup[(size_t)d2 * F + f];
        acc += w3 * sup[(size_t)d3 * F + f];
    }
    for (; i < e; i++) acc += ewl[i] * sup[(size_t)edst[i] * F + f];
    out[(size_t)n * F + f] = acc;
}

// ---------------- row L2-normalize: z = h / max(||h||, 1e-12), EMB=64 ----------------

__global__ __launch_bounds__(256) void k_norm(const float* __restrict__ h, float* __restrict__ z) {
    int lane = threadIdx.x & 63;
    int row = (blockIdx.x << 2) + (threadIdx.x >> 6);
    float v = h[(size_t)row * EMB + lane];
    float sq = v * v;
#pragma unroll
    for (int o = 32; o; o >>= 1) sq += __shfl_xor(sq, o);
    z[(size_t)row * EMB + lane] = v / fmaxf(sqrtf(sq), 1e-12f);
}

// ---------------- decode: A = sigmoid(z @ z^T), symmetric upper-tri tiles ----------------
// 128x128 tile per block, 8x8 micro-tile, strided-by-16 row/col assignment so the
// XOR swizzle (col = f ^ (r&31)) is bank-conflict-free on both operand reads.
// Each block writes its tile AND the mirrored tile (A is symmetric); diagonal
// blocks double-write identical values (benign).

__global__ __launch_bounds__(256) void k_decode(const float* __restrict__ z, float* __restrict__ A) {
    __shared__ float Zi[128][EMB];
    __shared__ float Zj[128][EMB];

    // blockIdx.x -> (bi, bj), bi <= bj  (upper triangle incl. diagonal)
    int rem = blockIdx.x, bi = 0, rowlen = NT;
    while (rem >= rowlen) { rem -= rowlen; ++bi; --rowlen; }
    const int bj = bi + rem;
    const int i0 = bi * 128, j0 = bj * 128;

    const int tid = threadIdx.x;
    const int tx = tid & 15;    // col group: cols j0 + tx + 16*j
    const int ty = tid >> 4;    // row group: rows i0 + ty + 16*i

    // stage both 128-row panels, swizzled
#pragma unroll
    for (int it = 0; it < 8; it++) {
        int r = it * 16 + ty;
        int s = r & 31;
        float4 vi = *(const float4*)&z[(size_t)(i0 + r) * EMB + tx * 4];
        Zi[r][(tx * 4 + 0) ^ s] = vi.x;
        Zi[r][(tx * 4 + 1) ^ s] = vi.y;
        Zi[r][(tx * 4 + 2) ^ s] = vi.z;
        Zi[r][(tx * 4 + 3) ^ s] = vi.w;
        float4 vj = *(const float4*)&z[(size_t)(j0 + r) * EMB + tx * 4];
        Zj[r][(tx * 4 + 0) ^ s] = vj.x;
        Zj[r][(tx * 4 + 1) ^ s] = vj.y;
        Zj[r][(tx * 4 + 2) ^ s] = vj.z;
        Zj[r][(tx * 4 + 3) ^ s] = vj.w;
    }
    __syncthreads();

    float acc[8][8];
#pragma unroll
    for (int i = 0; i < 8; i++)
#pragma unroll
        for (int j = 0; j < 8; j++) acc[i][j] = 0.f;

#pragma unroll 4
    for (int k = 0; k < EMB; k++) {
        float a[8], b[8];
#pragma unroll
        for (int i = 0; i < 8; i++) {
            int r = ty + 16 * i;
            a[i] = Zi[r][k ^ (r & 31)];
        }
#pragma unroll
        for (int j = 0; j < 8; j++) {
            int r = tx + 16 * j;
            b[j] = Zj[r][k ^ (r & 31)];
        }
#pragma unroll
        for (int i = 0; i < 8; i++)
#pragma unroll
            for (int j = 0; j < 8; j++) acc[i][j] += a[i] * b[j];
    }

    // epilogue: sigmoid once, store tile + mirror
#pragma unroll
    for (int i = 0; i < 8; i++) {
        int rg = i0 + ty + 16 * i;
#pragma unroll
        for (int j = 0; j < 8; j++) {
            int cg = j0 + tx + 16 * j;
            float sv = 1.f / (1.f + __expf(-acc[i][j]));
            A[(size_t)rg * N_NODES + cg] = sv;
            A[(size_t)cg * N_NODES + rg] = sv;
        }
    }
}

// ---------------- launch ----------------

extern "C" void kernel_launch(void* const* d_in, const int* in_sizes, int n_in,
                              void* d_out, int out_size, void* d_ws, size_t ws_size,
                              hipStream_t stream) {
    const float* x  = (const float*)d_in[0];
    const int*   ei = (const int*)d_in[1];     // [2, E]: src row then dst row
    const float* ew = (const float*)d_in[2];
    const float* W1 = (const float*)d_in[3];
    const float* W2 = (const float*)d_in[4];
    float* out = (float*)d_out;
    float* z   = out + (size_t)N_NODES * N_NODES;  // z output region, also decode input

    float* ws       = (float*)d_ws;
    float* support1 = ws;                        // 8192*256
    float* h1       = support1 + 2097152;        // 8192*256
    float* support2 = h1 + 2097152;              // 8192*64
    float* h2       = support2 + 524288;         // 8192*64
    int*   offs     = (int*)(h2 + 524288);       // 8193 (pad to 8448)
    int*   cnt      = offs + 8448;               // 8192 (counts, then cursor)
    int*   edst     = cnt + 8192;                // E
    float* ewl      = (float*)(edst + NEDGE);    // E

    const int* src = ei;
    const int* dst = ei + NEDGE;

    // CSR build
    k_zero<<<32, 256, 0, stream>>>(cnt, N_NODES);
    k_count<<<NEDGE / 256, 256, 0, stream>>>(src, cnt);
    k_scan<<<1, 1024, 0, stream>>>(cnt, offs);
    k_fill<<<NEDGE / 256, 256, 0, stream>>>(src, dst, ew, cnt, edst, ewl);

    // layer 1
    gemm_f32<64, 64, 16, 4, 4><<<dim3(HID / 64, N_NODES / 64), 256, 0, stream>>>(x, W1, support1, N_NODES, HID, F_IN);
    spmm_f32<HID><<<N_NODES, HID, 0, stream>>>(support1, offs, edst, ewl, h1);

    // layer 2
    gemm_f32<32, 64, 16, 2, 4><<<dim3(EMB / 64, N_NODES / 32), 256, 0, stream>>>(h1, W2, support2, N_NODES, EMB, HID);
    spmm_f32<EMB><<<N_NODES, EMB, 0, stream>>>(support2, offs, edst, ewl, h2);

    // normalize + decode (upper-triangular tile grid: NT*(NT+1)/2 blocks)
    k_norm<<<N_NODES / 4, 256, 0, stream>>>(h2, z);
    k_decode<<<NT * (NT + 1) / 2, 256, 0, stream>>>(z, out);
}

// Round 5
// 482.852 us; speedup vs baseline: 1.0746x; 1.0746x over previous
//
#include <hip/hip_runtime.h>
#include <cstddef>

#define N_NODES 8192
#define F_IN    512
#define HID     256
#define EMB     64
#define NEDGE   262144
#define NT      (N_NODES / 128)   // 64 decode tiles per dim

// ---------------- CSR build ----------------

__global__ __launch_bounds__(256) void k_count(const int* __restrict__ src, int* __restrict__ cnt) {
    int e = blockIdx.x * 256 + threadIdx.x;
    if (e < NEDGE) atomicAdd(&cnt[src[e]], 1);
}

// single block, 1024 threads, scans 8192 counts -> exclusive offsets + cursor copy
__global__ __launch_bounds__(1024) void k_scan(int* __restrict__ cnt_cursor, int* __restrict__ offs) {
    __shared__ int part[1024];
    const int t = threadIdx.x;
    int v[8];
    int s = 0;
#pragma unroll
    for (int i = 0; i < 8; i++) { v[i] = cnt_cursor[t * 8 + i]; s += v[i]; }
    part[t] = s;
    __syncthreads();
    for (int off = 1; off < 1024; off <<= 1) {
        int x = (t >= off) ? part[t - off] : 0;
        __syncthreads();
        part[t] += x;
        __syncthreads();
    }
    int run = part[t] - s;  // exclusive prefix of this thread's chunk
#pragma unroll
    for (int i = 0; i < 8; i++) {
        offs[t * 8 + i] = run;
        cnt_cursor[t * 8 + i] = run;  // cursor for fill
        run += v[i];
    }
    if (t == 1023) offs[8192] = run;  // == NEDGE
}

__global__ __launch_bounds__(256) void k_fill(const int* __restrict__ src, const int* __restrict__ dst,
                                              const float* __restrict__ w, int* __restrict__ cursor,
                                              int* __restrict__ edst, float* __restrict__ ewl) {
    int e = blockIdx.x * 256 + threadIdx.x;
    if (e < NEDGE) {
        int p = atomicAdd(&cursor[src[e]], 1);
        edst[p] = dst[e];
        ewl[p]  = w[e];
    }
}

// ---------------- fp32 tiled GEMM: C[M,N] = A[M,K] @ B[K,N] ----------------
// threads = (BM/TM)*(BN/TN) == 256; M%BM==0, N%BN==0, K%BK==0; BK%4==0.

template <int BM, int BN, int BK, int TM, int TN>
__global__ __launch_bounds__(256) void gemm_f32(const float* __restrict__ A, const float* __restrict__ B,
                                                float* __restrict__ C, int M, int N, int K) {
    __shared__ float As[BK][BM];  // A stored transposed
    __shared__ float Bs[BK][BN];
    const int tid = threadIdx.x;
    const int tx = tid % (BN / TN);
    const int ty = tid / (BN / TN);
    const int m0 = blockIdx.y * BM, n0 = blockIdx.x * BN;

    float acc[TM][TN];
#pragma unroll
    for (int i = 0; i < TM; i++)
#pragma unroll
        for (int j = 0; j < TN; j++) acc[i][j] = 0.f;

    for (int kt = 0; kt < K; kt += BK) {
        // A tile: BM*BK elems, float4 per thread-iter, store transposed
        for (int idx = tid * 4; idx < BM * BK; idx += 256 * 4) {
            int r = idx / BK, c = idx % BK;
            float4 v = *(const float4*)&A[(size_t)(m0 + r) * K + kt + c];
            As[c + 0][r] = v.x; As[c + 1][r] = v.y; As[c + 2][r] = v.z; As[c + 3][r] = v.w;
        }
        // B tile: BK*BN elems, direct float4
        for (int idx = tid * 4; idx < BK * BN; idx += 256 * 4) {
            int r = idx / BN, c = idx % BN;
            *(float4*)&Bs[r][c] = *(const float4*)&B[(size_t)(kt + r) * N + n0 + c];
        }
        __syncthreads();
#pragma unroll
        for (int k = 0; k < BK; k++) {
            float a[TM], b[TN];
            if constexpr (TM == 4) {
                float4 va = *(const float4*)&As[k][ty * TM];
                a[0] = va.x; a[1] = va.y; a[2] = va.z; a[3] = va.w;
            } else {
                float2 va = *(const float2*)&As[k][ty * TM];
                a[0] = va.x; a[1] = va.y;
            }
            if constexpr (TN == 4) {
                float4 vb = *(const float4*)&Bs[k][tx * TN];
                b[0] = vb.x; b[1] = vb.y; b[2] = vb.z; b[3] = vb.w;
            } else {
                float2 vb = *(const float2*)&Bs[k][tx * TN];
                b[0] = vb.x; b[1] = vb.y;
            }
#pragma unroll
            for (int i = 0; i < TM; i++)
#pragma unroll
                for (int j = 0; j < TN; j++) acc[i][j] += a[i] * b[j];
        }
        __syncthreads();
    }
#pragma unroll
    for (int i = 0; i < TM; i++) {
        size_t row = (size_t)(m0 + ty * TM + i);
#pragma unroll
        for (int j = 0; j < TN; j++) C[row * N + n0 + tx * TN + j] = acc[i][j];
    }
}

// ---------------- SpMM: out[n] = sum_e w_e * sup[dst_e], CSR gather, float4/lane ----------------
// F floats per node; LPN = F/4 lanes cover one node; NPW = 64/LPN nodes per wave.

template <int F>
__global__ __launch_bounds__(256) void spmm_f32(const float* __restrict__ sup, const int* __restrict__ offs,
                                                const int* __restrict__ edst, const float* __restrict__ ewl,
                                                float* __restrict__ out) {
    constexpr int LPN = F / 4;
    constexpr int NPW = 64 / LPN;
    const int lane = threadIdx.x & 63;
    const int wv = threadIdx.x >> 6;
    const int node = blockIdx.x * (4 * NPW) + wv * NPW + lane / LPN;
    const int f4 = (lane % LPN) * 4;
    const int s = offs[node], e = offs[node + 1];
    float4 acc = {0.f, 0.f, 0.f, 0.f};
    int i = s;
    for (; i + 2 <= e; i += 2) {
        int   d0 = edst[i],     d1 = edst[i + 1];
        float w0 = ewl[i],      w1 = ewl[i + 1];
        float4 v0 = *(const float4*)&sup[(size_t)d0 * F + f4];
        float4 v1 = *(const float4*)&sup[(size_t)d1 * F + f4];
        acc.x = fmaf(w0, v0.x, acc.x); acc.y = fmaf(w0, v0.y, acc.y);
        acc.z = fmaf(w0, v0.z, acc.z); acc.w = fmaf(w0, v0.w, acc.w);
        acc.x = fmaf(w1, v1.x, acc.x); acc.y = fmaf(w1, v1.y, acc.y);
        acc.z = fmaf(w1, v1.z, acc.z); acc.w = fmaf(w1, v1.w, acc.w);
    }
    if (i < e) {
        float w0 = ewl[i];
        float4 v0 = *(const float4*)&sup[(size_t)edst[i] * F + f4];
        acc.x = fmaf(w0, v0.x, acc.x); acc.y = fmaf(w0, v0.y, acc.y);
        acc.z = fmaf(w0, v0.z, acc.z); acc.w = fmaf(w0, v0.w, acc.w);
    }
    *(float4*)&out[(size_t)node * F + f4] = acc;
}

// ---------------- SpMM layer-2 fused with row L2-normalize (F=64) ----------------
// 16 lanes per node; after accumulation, reduce ||h||^2 across the 16-lane group
// (shfl_xor masks 1,2,4,8 stay in-group) and scale before the single store.

__global__ __launch_bounds__(256) void spmm_norm(const float* __restrict__ sup, const int* __restrict__ offs,
                                                 const int* __restrict__ edst, const float* __restrict__ ewl,
                                                 float* __restrict__ z) {
    constexpr int F = EMB;
    constexpr int LPN = F / 4;   // 16
    constexpr int NPW = 64 / LPN; // 4
    const int lane = threadIdx.x & 63;
    const int wv = threadIdx.x >> 6;
    const int node = blockIdx.x * (4 * NPW) + wv * NPW + lane / LPN;
    const int f4 = (lane % LPN) * 4;
    const int s = offs[node], e = offs[node + 1];
    float4 acc = {0.f, 0.f, 0.f, 0.f};
    int i = s;
    for (; i + 2 <= e; i += 2) {
        int   d0 = edst[i],     d1 = edst[i + 1];
        float w0 = ewl[i],      w1 = ewl[i + 1];
        float4 v0 = *(const float4*)&sup[(size_t)d0 * F + f4];
        float4 v1 = *(const float4*)&sup[(size_t)d1 * F + f4];
        acc.x = fmaf(w0, v0.x, acc.x); acc.y = fmaf(w0, v0.y, acc.y);
        acc.z = fmaf(w0, v0.z, acc.z); acc.w = fmaf(w0, v0.w, acc.w);
        acc.x = fmaf(w1, v1.x, acc.x); acc.y = fmaf(w1, v1.y, acc.y);
        acc.z = fmaf(w1, v1.z, acc.z); acc.w = fmaf(w1, v1.w, acc.w);
    }
    if (i < e) {
        float w0 = ewl[i];
        float4 v0 = *(const float4*)&sup[(size_t)edst[i] * F + f4];
        acc.x = fmaf(w0, v0.x, acc.x); acc.y = fmaf(w0, v0.y, acc.y);
        acc.z = fmaf(w0, v0.z, acc.z); acc.w = fmaf(w0, v0.w, acc.w);
    }
    float sq = acc.x * acc.x + acc.y * acc.y + acc.z * acc.z + acc.w * acc.w;
#pragma unroll
    for (int m = 1; m < LPN; m <<= 1) sq += __shfl_xor(sq, m);
    float inv = 1.f / fmaxf(sqrtf(sq), 1e-12f);
    acc.x *= inv; acc.y *= inv; acc.z *= inv; acc.w *= inv;
    *(float4*)&z[(size_t)node * F + f4] = acc;
}

// ---------------- decode: A = sigmoid(z @ z^T), symmetric upper-tri tiles ----------------
// 128x128 tile per block. Thread (tx,ty): rows ty+16i (i<8), cols 4tx+l+64jj (l<4, jj<2).
// Tile stores: coalesced float4. Mirror: LDS transpose stage (aliases Zi after compute),
// XOR-swizzled col' = c ^ ((tx&7)<<2) -> 2-way-free writes, float4-contiguous reads.

__global__ __launch_bounds__(256) void k_decode(const float* __restrict__ z, float* __restrict__ A) {
    __shared__ __align__(16) char smem[64 * 1024];
    float (*Zi)[EMB]   = (float(*)[EMB])smem;               // 128 x 64 (32KB)
    float (*Zj)[EMB]   = (float(*)[EMB])(smem + 32 * 1024); // 128 x 64 (32KB)
    float (*Stage)[128] = (float(*)[128])smem;              // 64 x 128, aliases Zi

    // blockIdx.x -> (bi, bj), bi <= bj (upper triangle incl. diagonal)
    int rem = blockIdx.x, bi = 0, rowlen = NT;
    while (rem >= rowlen) { rem -= rowlen; ++bi; --rowlen; }
    const int bj = bi + rem;
    const int i0 = bi * 128, j0 = bj * 128;

    const int tid = threadIdx.x;
    const int tx = tid & 15;   // col group
    const int ty = tid >> 4;   // row group

    // stage both 128-row panels, swizzled (col = f ^ (r&31))
#pragma unroll
    for (int it = 0; it < 8; it++) {
        int r = it * 16 + ty;
        int s = r & 31;
        float4 vi = *(const float4*)&z[(size_t)(i0 + r) * EMB + tx * 4];
        Zi[r][(tx * 4 + 0) ^ s] = vi.x;
        Zi[r][(tx * 4 + 1) ^ s] = vi.y;
        Zi[r][(tx * 4 + 2) ^ s] = vi.z;
        Zi[r][(tx * 4 + 3) ^ s] = vi.w;
        float4 vj = *(const float4*)&z[(size_t)(j0 + r) * EMB + tx * 4];
        Zj[r][(tx * 4 + 0) ^ s] = vj.x;
        Zj[r][(tx * 4 + 1) ^ s] = vj.y;
        Zj[r][(tx * 4 + 2) ^ s] = vj.z;
        Zj[r][(tx * 4 + 3) ^ s] = vj.w;
    }
    __syncthreads();

    float4 acc[8][2];
#pragma unroll
    for (int i = 0; i < 8; i++)
#pragma unroll
        for (int jj = 0; jj < 2; jj++) acc[i][jj] = make_float4(0.f, 0.f, 0.f, 0.f);

#pragma unroll 4
    for (int k = 0; k < EMB; k++) {
        float a[8];
#pragma unroll
        for (int i = 0; i < 8; i++) {
            int r = ty + 16 * i;
            a[i] = Zi[r][k ^ (r & 31)];  // broadcast across tx
        }
        float b[2][4];
#pragma unroll
        for (int jj = 0; jj < 2; jj++)
#pragma unroll
            for (int l = 0; l < 4; l++) {
                int r = 4 * tx + 64 * jj + l;
                b[jj][l] = Zj[r][k ^ (r & 31)];  // 2-way per bank (free)
            }
#pragma unroll
        for (int i = 0; i < 8; i++)
#pragma unroll
            for (int jj = 0; jj < 2; jj++) {
                acc[i][jj].x = fmaf(a[i], b[jj][0], acc[i][jj].x);
                acc[i][jj].y = fmaf(a[i], b[jj][1], acc[i][jj].y);
                acc[i][jj].z = fmaf(a[i], b[jj][2], acc[i][jj].z);
                acc[i][jj].w = fmaf(a[i], b[jj][3], acc[i][jj].w);
            }
    }
    __syncthreads();  // all Zi/Zj reads done; Stage may overwrite Zi region

    const int swx = (tx & 7) << 2;  // stage-column XOR (bits 2..4)
#pragma unroll
    for (int jj = 0; jj < 2; jj++) {
        // sigmoid + coalesced tile store + stage for mirror
#pragma unroll
        for (int i = 0; i < 8; i++) {
            int c = ty + 16 * i;  // local row in tile == column in mirror sub-tile
            float4 v = acc[i][jj];
            v.x = 1.f / (1.f + __expf(-v.x));
            v.y = 1.f / (1.f + __expf(-v.y));
            v.z = 1.f / (1.f + __expf(-v.z));
            v.w = 1.f / (1.f + __expf(-v.w));
            *(float4*)&A[(size_t)(i0 + c) * N_NODES + j0 + 64 * jj + 4 * tx] = v;
            int cs = c ^ swx;
            Stage[4 * tx + 0][cs] = v.x;
            Stage[4 * tx + 1][cs] = v.y;
            Stage[4 * tx + 2][cs] = v.z;
            Stage[4 * tx + 3][cs] = v.w;
        }
        __syncthreads();
        // coalesced mirror store: 64 rows x 128 cols, float4 per thread x8
#pragma unroll
        for (int it = 0; it < 8; it++) {
            int f = it * 1024 + tid * 4;
            int r2 = f >> 7;          // 0..63
            int cb = f & 127;         // float4-aligned col
            int cs = cb ^ (((r2 >> 2) & 7) << 2);
            float4 v = *(const float4*)&Stage[r2][cs];
            *(float4*)&A[(size_t)(j0 + 64 * jj + r2) * N_NODES + i0 + cb] = v;
        }
        __syncthreads();
    }
}

// ---------------- launch ----------------

extern "C" void kernel_launch(void* const* d_in, const int* in_sizes, int n_in,
                              void* d_out, int out_size, void* d_ws, size_t ws_size,
                              hipStream_t stream) {
    const float* x  = (const float*)d_in[0];
    const int*   ei = (const int*)d_in[1];     // [2, E]: src row then dst row
    const float* ew = (const float*)d_in[2];
    const float* W1 = (const float*)d_in[3];
    const float* W2 = (const float*)d_in[4];
    float* out = (float*)d_out;
    float* z   = out + (size_t)N_NODES * N_NODES;  // z output region, also decode input

    float* ws       = (float*)d_ws;
    float* support1 = ws;                        // 8192*256
    float* h1       = support1 + 2097152;        // 8192*256
    float* support2 = h1 + 2097152;              // 8192*64
    int*   offs     = (int*)(support2 + 524288); // 8193 (pad to 8448)
    int*   cnt      = offs + 8448;               // 8192 (counts, then cursor)
    int*   edst     = cnt + 8192;                // E
    float* ewl      = (float*)(edst + NEDGE);    // E

    const int* src = ei;
    const int* dst = ei + NEDGE;

    // CSR build (cnt zeroed via async memset — capture-legal, saves a launch)
    hipMemsetAsync(cnt, 0, N_NODES * sizeof(int), stream);
    k_count<<<NEDGE / 256, 256, 0, stream>>>(src, cnt);
    k_scan<<<1, 1024, 0, stream>>>(cnt, offs);
    k_fill<<<NEDGE / 256, 256, 0, stream>>>(src, dst, ew, cnt, edst, ewl);

    // layer 1
    gemm_f32<64, 64, 32, 4, 4><<<dim3(HID / 64, N_NODES / 64), 256, 0, stream>>>(x, W1, support1, N_NODES, HID, F_IN);
    spmm_f32<HID><<<N_NODES / 4, 256, 0, stream>>>(support1, offs, edst, ewl, h1);

    // layer 2 (SpMM fused with row-normalize writes z directly)
    gemm_f32<32, 64, 32, 2, 4><<<dim3(EMB / 64, N_NODES / 32), 256, 0, stream>>>(h1, W2, support2, N_NODES, EMB, HID);
    spmm_norm<<<N_NODES / 16, 256, 0, stream>>>(support2, offs, edst, ewl, z);

    // decode (upper-triangular tile grid)
    k_decode<<<NT * (NT + 1) / 2, 256, 0, stream>>>(z, out);
}

// Round 6
// 438.737 us; speedup vs baseline: 1.1826x; 1.1006x over previous
//
#include <hip/hip_runtime.h>
#include <cstddef>

#define N_NODES 8192
#define F_IN    512
#define HID     256
#define EMB     64
#define NEDGE   262144

typedef _Float16 half8  __attribute__((ext_vector_type(8)));
typedef _Float16 half4h __attribute__((ext_vector_type(4)));
typedef float    floatx4 __attribute__((ext_vector_type(4)));

// ---------------- CSR build ----------------

__global__ __launch_bounds__(256) void k_count(const int* __restrict__ src, int* __restrict__ cnt) {
    int e = blockIdx.x * 256 + threadIdx.x;
    if (e < NEDGE) atomicAdd(&cnt[src[e]], 1);
}

// single block, 1024 threads, scans 8192 counts -> exclusive offsets + cursor copy
__global__ __launch_bounds__(1024) void k_scan(int* __restrict__ cnt_cursor, int* __restrict__ offs) {
    __shared__ int part[1024];
    const int t = threadIdx.x;
    int v[8];
    int s = 0;
#pragma unroll
    for (int i = 0; i < 8; i++) { v[i] = cnt_cursor[t * 8 + i]; s += v[i]; }
    part[t] = s;
    __syncthreads();
    for (int off = 1; off < 1024; off <<= 1) {
        int x = (t >= off) ? part[t - off] : 0;
        __syncthreads();
        part[t] += x;
        __syncthreads();
    }
    int run = part[t] - s;  // exclusive prefix of this thread's chunk
#pragma unroll
    for (int i = 0; i < 8; i++) {
        offs[t * 8 + i] = run;
        cnt_cursor[t * 8 + i] = run;  // cursor for fill
        run += v[i];
    }
    if (t == 1023) offs[8192] = run;  // == NEDGE
}

__global__ __launch_bounds__(256) void k_fill(const int* __restrict__ src, const int* __restrict__ dst,
                                              const float* __restrict__ w, int* __restrict__ cursor,
                                              int* __restrict__ edst, float* __restrict__ ewl) {
    int e = blockIdx.x * 256 + threadIdx.x;
    if (e < NEDGE) {
        int p = atomicAdd(&cursor[src[e]], 1);
        edst[p] = dst[e];
        ewl[p]  = w[e];
    }
}

// ---------------- fp32 tiled GEMM: C[M,N] = A[M,K] @ B[K,N] ----------------
// threads = (BM/TM)*(BN/TN) == 256; M%BM==0, N%BN==0, K%BK==0; BK%4==0.

template <int BM, int BN, int BK, int TM, int TN>
__global__ __launch_bounds__(256) void gemm_f32(const float* __restrict__ A, const float* __restrict__ B,
                                                float* __restrict__ C, int M, int N, int K) {
    __shared__ float As[BK][BM];  // A stored transposed
    __shared__ float Bs[BK][BN];
    const int tid = threadIdx.x;
    const int tx = tid % (BN / TN);
    const int ty = tid / (BN / TN);
    const int m0 = blockIdx.y * BM, n0 = blockIdx.x * BN;

    float acc[TM][TN];
#pragma unroll
    for (int i = 0; i < TM; i++)
#pragma unroll
        for (int j = 0; j < TN; j++) acc[i][j] = 0.f;

    for (int kt = 0; kt < K; kt += BK) {
        for (int idx = tid * 4; idx < BM * BK; idx += 256 * 4) {
            int r = idx / BK, c = idx % BK;
            float4 v = *(const float4*)&A[(size_t)(m0 + r) * K + kt + c];
            As[c + 0][r] = v.x; As[c + 1][r] = v.y; As[c + 2][r] = v.z; As[c + 3][r] = v.w;
        }
        for (int idx = tid * 4; idx < BK * BN; idx += 256 * 4) {
            int r = idx / BN, c = idx % BN;
            *(float4*)&Bs[r][c] = *(const float4*)&B[(size_t)(kt + r) * N + n0 + c];
        }
        __syncthreads();
#pragma unroll
        for (int k = 0; k < BK; k++) {
            float a[TM], b[TN];
            if constexpr (TM == 4) {
                float4 va = *(const float4*)&As[k][ty * TM];
                a[0] = va.x; a[1] = va.y; a[2] = va.z; a[3] = va.w;
            } else {
                float2 va = *(const float2*)&As[k][ty * TM];
                a[0] = va.x; a[1] = va.y;
            }
            if constexpr (TN == 4) {
                float4 vb = *(const float4*)&Bs[k][tx * TN];
                b[0] = vb.x; b[1] = vb.y; b[2] = vb.z; b[3] = vb.w;
            } else {
                float2 vb = *(const float2*)&Bs[k][tx * TN];
                b[0] = vb.x; b[1] = vb.y;
            }
#pragma unroll
            for (int i = 0; i < TM; i++)
#pragma unroll
                for (int j = 0; j < TN; j++) acc[i][j] += a[i] * b[j];
        }
        __syncthreads();
    }
#pragma unroll
    for (int i = 0; i < TM; i++) {
        size_t row = (size_t)(m0 + ty * TM + i);
#pragma unroll
        for (int j = 0; j < TN; j++) C[row * N + n0 + tx * TN + j] = acc[i][j];
    }
}

// ---------------- SpMM feature-blocked: FB cols per pass (L2-resident slice) ----------------
// LPN = FB/4 lanes per node; NPW = 64/LPN nodes per wave; grid covers all nodes.

template <int F, int FB>
__global__ __launch_bounds__(256) void spmm_blk(const float* __restrict__ sup, const int* __restrict__ offs,
                                                const int* __restrict__ edst, const float* __restrict__ ewl,
                                                float* __restrict__ out, int foff) {
    constexpr int LPN = FB / 4;
    constexpr int NPW = 64 / LPN;
    const int lane = threadIdx.x & 63;
    const int wv = threadIdx.x >> 6;
    const int node = blockIdx.x * (4 * NPW) + wv * NPW + lane / LPN;
    const int f4 = foff + (lane % LPN) * 4;
    const int s = offs[node], e = offs[node + 1];
    float4 acc = {0.f, 0.f, 0.f, 0.f};
    int i = s;
    for (; i + 2 <= e; i += 2) {
        int   d0 = edst[i],     d1 = edst[i + 1];
        float w0 = ewl[i],      w1 = ewl[i + 1];
        float4 v0 = *(const float4*)&sup[(size_t)d0 * F + f4];
        float4 v1 = *(const float4*)&sup[(size_t)d1 * F + f4];
        acc.x = fmaf(w0, v0.x, acc.x); acc.y = fmaf(w0, v0.y, acc.y);
        acc.z = fmaf(w0, v0.z, acc.z); acc.w = fmaf(w0, v0.w, acc.w);
        acc.x = fmaf(w1, v1.x, acc.x); acc.y = fmaf(w1, v1.y, acc.y);
        acc.z = fmaf(w1, v1.z, acc.z); acc.w = fmaf(w1, v1.w, acc.w);
    }
    if (i < e) {
        float w0 = ewl[i];
        float4 v0 = *(const float4*)&sup[(size_t)edst[i] * F + f4];
        acc.x = fmaf(w0, v0.x, acc.x); acc.y = fmaf(w0, v0.y, acc.y);
        acc.z = fmaf(w0, v0.z, acc.z); acc.w = fmaf(w0, v0.w, acc.w);
    }
    *(float4*)&out[(size_t)node * F + f4] = acc;
}

// ---------------- SpMM layer-2 fused with L2-normalize; writes fp32 z AND f16 zh ----------------

__global__ __launch_bounds__(256) void spmm_norm(const float* __restrict__ sup, const int* __restrict__ offs,
                                                 const int* __restrict__ edst, const float* __restrict__ ewl,
                                                 float* __restrict__ z, _Float16* __restrict__ zh) {
    constexpr int F = EMB;
    constexpr int LPN = F / 4;    // 16
    constexpr int NPW = 64 / LPN; // 4
    const int lane = threadIdx.x & 63;
    const int wv = threadIdx.x >> 6;
    const int node = blockIdx.x * (4 * NPW) + wv * NPW + lane / LPN;
    const int f4 = (lane % LPN) * 4;
    const int s = offs[node], e = offs[node + 1];
    float4 acc = {0.f, 0.f, 0.f, 0.f};
    int i = s;
    for (; i + 2 <= e; i += 2) {
        int   d0 = edst[i],     d1 = edst[i + 1];
        float w0 = ewl[i],      w1 = ewl[i + 1];
        float4 v0 = *(const float4*)&sup[(size_t)d0 * F + f4];
        float4 v1 = *(const float4*)&sup[(size_t)d1 * F + f4];
        acc.x = fmaf(w0, v0.x, acc.x); acc.y = fmaf(w0, v0.y, acc.y);
        acc.z = fmaf(w0, v0.z, acc.z); acc.w = fmaf(w0, v0.w, acc.w);
        acc.x = fmaf(w1, v1.x, acc.x); acc.y = fmaf(w1, v1.y, acc.y);
        acc.z = fmaf(w1, v1.z, acc.z); acc.w = fmaf(w1, v1.w, acc.w);
    }
    if (i < e) {
        float w0 = ewl[i];
        float4 v0 = *(const float4*)&sup[(size_t)edst[i] * F + f4];
        acc.x = fmaf(w0, v0.x, acc.x); acc.y = fmaf(w0, v0.y, acc.y);
        acc.z = fmaf(w0, v0.z, acc.z); acc.w = fmaf(w0, v0.w, acc.w);
    }
    float sq = acc.x * acc.x + acc.y * acc.y + acc.z * acc.z + acc.w * acc.w;
#pragma unroll
    for (int m = 1; m < LPN; m <<= 1) sq += __shfl_xor(sq, m);
    float inv = 1.f / fmaxf(sqrtf(sq), 1e-12f);
    acc.x *= inv; acc.y *= inv; acc.z *= inv; acc.w *= inv;
    *(float4*)&z[(size_t)node * F + f4] = acc;
    half4h h;
    h.x = (_Float16)acc.x; h.y = (_Float16)acc.y; h.z = (_Float16)acc.z; h.w = (_Float16)acc.w;
    *(half4h*)&zh[(size_t)node * F + f4] = h;
}

// ---------------- decode: A = sigmoid(zh @ zh^T) via f16 MFMA, no LDS ----------------
// Block = 128x128 tile, 4 waves; wave w owns rows [w*32, w*32+32) = 2 row-tiles x 8 col-tiles
// of 16x16x32 MFMA. Fragments are contiguous 16B z-row chunks loaded straight from global
// (zh = 1MB, L2-resident). A/B k-permutation errors cancel (same perm both operands);
// C/D layout col=lane&15, row=(lane>>4)*4+reg is HW-verified (m89/m91, dtype-independent).

__global__ __launch_bounds__(256) void k_decode(const _Float16* __restrict__ zh, float* __restrict__ A) {
    const int i0 = blockIdx.y * 128;
    const int j0 = blockIdx.x * 128;
    const int lane = threadIdx.x & 63;
    const int wave = threadIdx.x >> 6;
    const int l16 = lane & 15;
    const int koff = (lane >> 4) * 8;

    half8 a[2][2], b[8][2];
#pragma unroll
    for (int rt = 0; rt < 2; rt++)
#pragma unroll
        for (int s = 0; s < 2; s++)
            a[rt][s] = *(const half8*)&zh[(size_t)(i0 + wave * 32 + rt * 16 + l16) * EMB + s * 32 + koff];
#pragma unroll
    for (int ct = 0; ct < 8; ct++)
#pragma unroll
        for (int s = 0; s < 2; s++)
            b[ct][s] = *(const half8*)&zh[(size_t)(j0 + ct * 16 + l16) * EMB + s * 32 + koff];

    floatx4 acc[2][8];
#pragma unroll
    for (int rt = 0; rt < 2; rt++)
#pragma unroll
        for (int ct = 0; ct < 8; ct++)
            acc[rt][ct] = (floatx4){0.f, 0.f, 0.f, 0.f};

#pragma unroll
    for (int s = 0; s < 2; s++)
#pragma unroll
        for (int rt = 0; rt < 2; rt++)
#pragma unroll
            for (int ct = 0; ct < 8; ct++)
                acc[rt][ct] = __builtin_amdgcn_mfma_f32_16x16x32_f16(a[rt][s], b[ct][s], acc[rt][ct], 0, 0, 0);

    const int rbase = (lane >> 4) * 4;
#pragma unroll
    for (int rt = 0; rt < 2; rt++)
#pragma unroll
        for (int r = 0; r < 4; r++) {
            size_t row = (size_t)(i0 + wave * 32 + rt * 16 + rbase + r);
#pragma unroll
            for (int ct = 0; ct < 8; ct++) {
                float v = acc[rt][ct][r];
                A[row * N_NODES + j0 + ct * 16 + l16] = 1.f / (1.f + __expf(-v));
            }
        }
}

// ---------------- launch ----------------

extern "C" void kernel_launch(void* const* d_in, const int* in_sizes, int n_in,
                              void* d_out, int out_size, void* d_ws, size_t ws_size,
                              hipStream_t stream) {
    const float* x  = (const float*)d_in[0];
    const int*   ei = (const int*)d_in[1];     // [2, E]: src row then dst row
    const float* ew = (const float*)d_in[2];
    const float* W1 = (const float*)d_in[3];
    const float* W2 = (const float*)d_in[4];
    float* out = (float*)d_out;
    float* z   = out + (size_t)N_NODES * N_NODES;  // fp32 z output region

    float* ws       = (float*)d_ws;
    float* support1 = ws;                        // 8192*256
    float* h1       = support1 + 2097152;        // 8192*256
    float* support2 = h1 + 2097152;              // 8192*64
    int*   offs     = (int*)(support2 + 524288); // 8193 (pad to 8448)
    int*   cnt      = offs + 8448;               // 8192 (counts, then cursor)
    int*   edst     = cnt + 8192;                // E
    float* ewl      = (float*)(edst + NEDGE);    // E
    _Float16* zh    = (_Float16*)(ewl + NEDGE);  // 8192*64 f16 (1MB)

    const int* src = ei;
    const int* dst = ei + NEDGE;

    // CSR build
    hipMemsetAsync(cnt, 0, N_NODES * sizeof(int), stream);
    k_count<<<NEDGE / 256, 256, 0, stream>>>(src, cnt);
    k_scan<<<1, 1024, 0, stream>>>(cnt, offs);
    k_fill<<<NEDGE / 256, 256, 0, stream>>>(src, dst, ew, cnt, edst, ewl);

    // layer 1 (SpMM in two 128-col passes: 4MB slice stays L2-resident)
    gemm_f32<64, 64, 32, 4, 4><<<dim3(HID / 64, N_NODES / 64), 256, 0, stream>>>(x, W1, support1, N_NODES, HID, F_IN);
    spmm_blk<HID, 128><<<N_NODES / 8, 256, 0, stream>>>(support1, offs, edst, ewl, h1, 0);
    spmm_blk<HID, 128><<<N_NODES / 8, 256, 0, stream>>>(support1, offs, edst, ewl, h1, 128);

    // layer 2 (SpMM fused with row-normalize; writes fp32 z and f16 zh)
    gemm_f32<32, 64, 32, 2, 4><<<dim3(EMB / 64, N_NODES / 32), 256, 0, stream>>>(h1, W2, support2, N_NODES, EMB, HID);
    spmm_norm<<<N_NODES / 16, 256, 0, stream>>>(support2, offs, edst, ewl, z, zh);

    // decode: dense 64x64 tile grid, MFMA, no LDS
    k_decode<<<dim3(N_NODES / 128, N_NODES / 128), 256, 0, stream>>>(zh, out);
}

// Round 8
// 391.172 us; speedup vs baseline: 1.3264x; 1.1216x over previous
//
#include <hip/hip_runtime.h>
#include <cstddef>

#define N_NODES 8192
#define F_IN    512
#define HID     256
#define EMB     64
#define NEDGE   262144

typedef _Float16 half8  __attribute__((ext_vector_type(8)));
typedef _Float16 half4h __attribute__((ext_vector_type(4)));
typedef float    floatx4 __attribute__((ext_vector_type(4)));

// ---------------- CSR build ----------------

__global__ __launch_bounds__(256) void k_count(const int* __restrict__ src, int* __restrict__ cnt) {
    int e = blockIdx.x * 256 + threadIdx.x;
    if (e < NEDGE) atomicAdd(&cnt[src[e]], 1);
}

__global__ __launch_bounds__(1024) void k_scan(int* __restrict__ cnt_cursor, int* __restrict__ offs) {
    __shared__ int part[1024];
    const int t = threadIdx.x;
    int v[8];
    int s = 0;
#pragma unroll
    for (int i = 0; i < 8; i++) { v[i] = cnt_cursor[t * 8 + i]; s += v[i]; }
    part[t] = s;
    __syncthreads();
    for (int off = 1; off < 1024; off <<= 1) {
        int x = (t >= off) ? part[t - off] : 0;
        __syncthreads();
        part[t] += x;
        __syncthreads();
    }
    int run = part[t] - s;
#pragma unroll
    for (int i = 0; i < 8; i++) {
        offs[t * 8 + i] = run;
        cnt_cursor[t * 8 + i] = run;
        run += v[i];
    }
    if (t == 1023) offs[8192] = run;
}

__global__ __launch_bounds__(256) void k_fill(const int* __restrict__ src, const int* __restrict__ dst,
                                              const float* __restrict__ w, int* __restrict__ cursor,
                                              int* __restrict__ edst, float* __restrict__ ewl) {
    int e = blockIdx.x * 256 + threadIdx.x;
    if (e < NEDGE) {
        int p = atomicAdd(&cursor[src[e]], 1);
        edst[p] = dst[e];
        ewl[p]  = w[e];
    }
}

// ---------------- fp32 -> f16 converts ----------------

__global__ __launch_bounds__(256) void k_cvt_x(const float* __restrict__ x, _Float16* __restrict__ xh) {
    int i = (blockIdx.x * 256 + threadIdx.x) * 4;   // grid covers N_NODES*F_IN exactly
    float4 v = *(const float4*)&x[i];
    half4h h = { (_Float16)v.x, (_Float16)v.y, (_Float16)v.z, (_Float16)v.w };
    *(half4h*)&xh[i] = h;
}

// W1 [512][256] -> W1T [256][512]; W2 [256][64] -> W2T [64][256]
__global__ __launch_bounds__(256) void k_cvt_w(const float* __restrict__ W1, const float* __restrict__ W2,
                                               _Float16* __restrict__ W1T, _Float16* __restrict__ W2T) {
    int t = blockIdx.x * 256 + threadIdx.x;
    if (t < F_IN * HID) {
        int r = t >> 8, c = t & 255;
        W1T[c * F_IN + r] = (_Float16)W1[t];
    } else if (t < F_IN * HID + HID * EMB) {
        int u = t - F_IN * HID;
        int r = u >> 6, c = u & 63;
        W2T[c * HID + r] = (_Float16)W2[u];
    }
}

// ---------------- MFMA f16 GEMM: C[M,N] = Ah[M,K] @ BT[N,K]^T ----------------
// Wave: 16 rows x CT 16-col tiles, full K. Block = 4 waves = 64 rows.
// Both fragments are contiguous 16B row chunks; k-permutation cancels between operands
// (established by the round-6 decode pass); C/D layout is the m89/m91 HW-verified mapping.

template <int K, int N, int CT, bool OUT_HALF>
__global__ __launch_bounds__(256) void gemm_mfma(const _Float16* __restrict__ Ah,
                                                 const _Float16* __restrict__ BT,
                                                 _Float16* __restrict__ Ch,
                                                 float* __restrict__ Cf) {
    const int lane = threadIdx.x & 63;
    const int wave = threadIdx.x >> 6;
    const int row0 = blockIdx.y * 64 + wave * 16;
    const int col0 = blockIdx.x * (CT * 16);
    const int l16 = lane & 15;
    const int koff = (lane >> 4) * 8;

    floatx4 acc[CT];
#pragma unroll
    for (int ct = 0; ct < CT; ct++) acc[ct] = (floatx4){0.f, 0.f, 0.f, 0.f};

#pragma unroll
    for (int ks = 0; ks < K / 32; ks++) {
        half8 a = *(const half8*)&Ah[(size_t)(row0 + l16) * K + ks * 32 + koff];
#pragma unroll
        for (int ct = 0; ct < CT; ct++) {
            half8 b = *(const half8*)&BT[(size_t)(col0 + ct * 16 + l16) * K + ks * 32 + koff];
            acc[ct] = __builtin_amdgcn_mfma_f32_16x16x32_f16(a, b, acc[ct], 0, 0, 0);
        }
    }

    const int rb = (lane >> 4) * 4;
#pragma unroll
    for (int ct = 0; ct < CT; ct++)
#pragma unroll
        for (int r = 0; r < 4; r++) {
            size_t row = (size_t)(row0 + rb + r);
            int col = col0 + ct * 16 + l16;
            if constexpr (OUT_HALF) Ch[row * N + col] = (_Float16)acc[ct][r];
            else                    Cf[row * N + col] = acc[ct][r];
        }
}

// ---------------- SpMM layer 1: h1h[n] = sum_e w_e * s1h[dst_e], one node per wave ----------------
// node is wave-uniform (readfirstlane) -> offs/edst/ewl become scalar loads.
// Lane covers 4 f16 cols (half4 = 8B); f32 accumulate; f16 store.

__global__ __launch_bounds__(256) void spmm_h(const _Float16* __restrict__ sup, const int* __restrict__ offs,
                                              const int* __restrict__ edst, const float* __restrict__ ewl,
                                              _Float16* __restrict__ outh) {
    const int lane = threadIdx.x & 63;
    const int node = __builtin_amdgcn_readfirstlane(blockIdx.x * 4 + (threadIdx.x >> 6));
    const int s = offs[node], e = offs[node + 1];
    floatx4 acc = {0.f, 0.f, 0.f, 0.f};
    int i = s;
    for (; i + 2 <= e; i += 2) {
        int   d0 = edst[i],    d1 = edst[i + 1];
        float w0 = ewl[i],     w1 = ewl[i + 1];
        half4h v0 = *(const half4h*)&sup[(size_t)d0 * HID + lane * 4];
        half4h v1 = *(const half4h*)&sup[(size_t)d1 * HID + lane * 4];
        acc.x = fmaf(w0, (float)v0.x, acc.x); acc.y = fmaf(w0, (float)v0.y, acc.y);
        acc.z = fmaf(w0, (float)v0.z, acc.z); acc.w = fmaf(w0, (float)v0.w, acc.w);
        acc.x = fmaf(w1, (float)v1.x, acc.x); acc.y = fmaf(w1, (float)v1.y, acc.y);
        acc.z = fmaf(w1, (float)v1.z, acc.z); acc.w = fmaf(w1, (float)v1.w, acc.w);
    }
    if (i < e) {
        float w0 = ewl[i];
        half4h v0 = *(const half4h*)&sup[(size_t)edst[i] * HID + lane * 4];
        acc.x = fmaf(w0, (float)v0.x, acc.x); acc.y = fmaf(w0, (float)v0.y, acc.y);
        acc.z = fmaf(w0, (float)v0.z, acc.z); acc.w = fmaf(w0, (float)v0.w, acc.w);
    }
    half4h o = { (_Float16)acc.x, (_Float16)acc.y, (_Float16)acc.z, (_Float16)acc.w };
    *(half4h*)&outh[(size_t)node * HID + lane * 4] = o;
}

// ---------------- SpMM layer 2 + L2-normalize: one node per wave, 1 float per lane ----------------

__global__ __launch_bounds__(256) void spmm_norm(const float* __restrict__ sup, const int* __restrict__ offs,
                                                 const int* __restrict__ edst, const float* __restrict__ ewl,
                                                 float* __restrict__ z, _Float16* __restrict__ zh) {
    const int lane = threadIdx.x & 63;
    const int node = __builtin_amdgcn_readfirstlane(blockIdx.x * 4 + (threadIdx.x >> 6));
    const int s = offs[node], e = offs[node + 1];
    float acc = 0.f;
    int i = s;
    for (; i + 2 <= e; i += 2) {
        acc = fmaf(ewl[i],     sup[(size_t)edst[i] * EMB + lane],     acc);
        acc = fmaf(ewl[i + 1], sup[(size_t)edst[i + 1] * EMB + lane], acc);
    }
    if (i < e) acc = fmaf(ewl[i], sup[(size_t)edst[i] * EMB + lane], acc);
    float sq = acc * acc;
#pragma unroll
    for (int m = 1; m < 64; m <<= 1) sq += __shfl_xor(sq, m);
    float inv = 1.f / fmaxf(sqrtf(sq), 1e-12f);
    acc *= inv;
    z[(size_t)node * EMB + lane] = acc;
    zh[(size_t)node * EMB + lane] = (_Float16)acc;
}

// ---------------- decode: A = sigmoid(zh @ zh^T) via f16 MFMA, no LDS (round-6, verified) ----------------

__global__ __launch_bounds__(256) void k_decode(const _Float16* __restrict__ zh, float* __restrict__ A) {
    const int i0 = blockIdx.y * 128;
    const int j0 = blockIdx.x * 128;
    const int lane = threadIdx.x & 63;
    const int wave = threadIdx.x >> 6;
    const int l16 = lane & 15;
    const int koff = (lane >> 4) * 8;

    half8 a[2][2], b[8][2];
#pragma unroll
    for (int rt = 0; rt < 2; rt++)
#pragma unroll
        for (int s = 0; s < 2; s++)
            a[rt][s] = *(const half8*)&zh[(size_t)(i0 + wave * 32 + rt * 16 + l16) * EMB + s * 32 + koff];
#pragma unroll
    for (int ct = 0; ct < 8; ct++)
#pragma unroll
        for (int s = 0; s < 2; s++)
            b[ct][s] = *(const half8*)&zh[(size_t)(j0 + ct * 16 + l16) * EMB + s * 32 + koff];

    floatx4 acc[2][8];
#pragma unroll
    for (int rt = 0; rt < 2; rt++)
#pragma unroll
        for (int ct = 0; ct < 8; ct++)
            acc[rt][ct] = (floatx4){0.f, 0.f, 0.f, 0.f};

#pragma unroll
    for (int s = 0; s < 2; s++)
#pragma unroll
        for (int rt = 0; rt < 2; rt++)
#pragma unroll
            for (int ct = 0; ct < 8; ct++)
                acc[rt][ct] = __builtin_amdgcn_mfma_f32_16x16x32_f16(a[rt][s], b[ct][s], acc[rt][ct], 0, 0, 0);

    const int rbase = (lane >> 4) * 4;
#pragma unroll
    for (int rt = 0; rt < 2; rt++)
#pragma unroll
        for (int r = 0; r < 4; r++) {
            size_t row = (size_t)(i0 + wave * 32 + rt * 16 + rbase + r);
#pragma unroll
            for (int ct = 0; ct < 8; ct++) {
                float v = acc[rt][ct][r];
                A[row * N_NODES + j0 + ct * 16 + l16] = 1.f / (1.f + __expf(-v));
            }
        }
}

// ---------------- launch ----------------

extern "C" void kernel_launch(void* const* d_in, const int* in_sizes, int n_in,
                              void* d_out, int out_size, void* d_ws, size_t ws_size,
                              hipStream_t stream) {
    const float* x  = (const float*)d_in[0];
    const int*   ei = (const int*)d_in[1];     // [2, E]: src row then dst row
    const float* ew = (const float*)d_in[2];
    const float* W1 = (const float*)d_in[3];
    const float* W2 = (const float*)d_in[4];
    float* out = (float*)d_out;
    float* z   = out + (size_t)N_NODES * N_NODES;  // fp32 z output region

    _Float16* xh   = (_Float16*)d_ws;            // 8 MB
    _Float16* W1T  = xh + (size_t)N_NODES * F_IN;      // 256 KB
    _Float16* W2T  = W1T + F_IN * HID;                 // 32 KB
    _Float16* s1h  = W2T + HID * EMB;                  // 4 MB  [8192][256]
    _Float16* h1h  = s1h + (size_t)N_NODES * HID;      // 4 MB  [8192][256]
    _Float16* zh   = h1h + (size_t)N_NODES * HID;      // 1 MB  [8192][64]
    float* s2      = (float*)(zh + (size_t)N_NODES * EMB);  // 2 MB [8192][64]
    int* offs      = (int*)(s2 + (size_t)N_NODES * EMB);    // 8448
    int* cnt       = offs + 8448;
    int* edst      = cnt + 8192;                 // E
    float* ewl     = (float*)(edst + NEDGE);     // E

    const int* src = ei;
    const int* dst = ei + NEDGE;

    // CSR build
    hipMemsetAsync(cnt, 0, N_NODES * sizeof(int), stream);
    k_count<<<NEDGE / 256, 256, 0, stream>>>(src, cnt);
    k_scan<<<1, 1024, 0, stream>>>(cnt, offs);
    k_fill<<<NEDGE / 256, 256, 0, stream>>>(src, dst, ew, cnt, edst, ewl);

    // converts
    k_cvt_x<<<(N_NODES * F_IN / 4) / 256, 256, 0, stream>>>(x, xh);
    k_cvt_w<<<(F_IN * HID + HID * EMB + 255) / 256, 256, 0, stream>>>(W1, W2, W1T, W2T);

    // layer 1: MFMA GEMM (f16 out) + wave-uniform f16 SpMM
    gemm_mfma<F_IN, HID, 4, true><<<dim3(HID / 64, N_NODES / 64), 256, 0, stream>>>(xh, W1T, s1h, nullptr);
    spmm_h<<<N_NODES / 4, 256, 0, stream>>>(s1h, offs, edst, ewl, h1h);

    // layer 2: MFMA GEMM (f32 out) + wave-uniform SpMM fused with normalize
    gemm_mfma<HID, EMB, 4, false><<<dim3(EMB / 64, N_NODES / 64), 256, 0, stream>>>(h1h, W2T, nullptr, s2);
    spmm_norm<<<N_NODES / 4, 256, 0, stream>>>(s2, offs, edst, ewl, z, zh);

    // decode: dense 64x64 tile grid, MFMA, no LDS
    k_decode<<<dim3(N_NODES / 128, N_NODES / 128), 256, 0, stream>>>(zh, out);
}

// Round 9
// 383.337 us; speedup vs baseline: 1.3535x; 1.0204x over previous
//
#include <hip/hip_runtime.h>
#include <cstddef>

#define N_NODES 8192
#define F_IN    512
#define HID     256
#define EMB     64
#define NEDGE   262144

typedef _Float16 half8  __attribute__((ext_vector_type(8)));
typedef _Float16 half4h __attribute__((ext_vector_type(4)));
typedef float    floatx4 __attribute__((ext_vector_type(4)));

// ---------------- CSR build ----------------

__global__ __launch_bounds__(256) void k_count(const int* __restrict__ src, int* __restrict__ cnt) {
    int e = blockIdx.x * 256 + threadIdx.x;
    if (e < NEDGE) atomicAdd(&cnt[src[e]], 1);
}

// single block, 1024 threads = 16 waves; wave-shfl scans, only 2 barriers
__global__ __launch_bounds__(1024) void k_scan(int* __restrict__ cnt_cursor, int* __restrict__ offs) {
    __shared__ int wsum[16], wexcl[16];
    const int t = threadIdx.x;
    const int lane = t & 63, wv = t >> 6;
    int v[8];
    int s = 0;
#pragma unroll
    for (int i = 0; i < 8; i++) { v[i] = cnt_cursor[t * 8 + i]; s += v[i]; }
    int incl = s;
#pragma unroll
    for (int off = 1; off < 64; off <<= 1) {
        int x = __shfl_up(incl, off);
        if (lane >= off) incl += x;
    }
    if (lane == 63) wsum[wv] = incl;
    __syncthreads();
    if (wv == 0 && lane < 16) {
        int ws = wsum[lane];
        int wincl = ws;
#pragma unroll
        for (int off = 1; off < 16; off <<= 1) {
            int x = __shfl_up(wincl, off);
            if (lane >= off) wincl += x;
        }
        wexcl[lane] = wincl - ws;
    }
    __syncthreads();
    int run = wexcl[wv] + (incl - s);  // exclusive prefix of this thread's chunk
#pragma unroll
    for (int i = 0; i < 8; i++) {
        offs[t * 8 + i] = run;
        cnt_cursor[t * 8 + i] = run;  // cursor for fill
        run += v[i];
    }
    if (t == 1023) offs[8192] = run;  // == NEDGE
}

// packed edge record: .x = dst node, .y = weight bits (single 8B store per edge)
__global__ __launch_bounds__(256) void k_fill(const int* __restrict__ src, const int* __restrict__ dst,
                                              const float* __restrict__ w, int* __restrict__ cursor,
                                              int2* __restrict__ epack) {
    int e = blockIdx.x * 256 + threadIdx.x;
    if (e < NEDGE) {
        int p = atomicAdd(&cursor[src[e]], 1);
        epack[p] = make_int2(dst[e], __float_as_int(w[e]));
    }
}

// ---------------- fp32 -> f16 converts (merged: x blocks [0,4096), W blocks [4096,4672)) ----------------

__global__ __launch_bounds__(256) void k_cvt(const float* __restrict__ x, const float* __restrict__ W1,
                                             const float* __restrict__ W2, _Float16* __restrict__ xh,
                                             _Float16* __restrict__ W1T, _Float16* __restrict__ W2T) {
    int b = blockIdx.x;
    if (b < (N_NODES * F_IN / 4) / 256) {
        int i = (b * 256 + threadIdx.x) * 4;
        float4 v = *(const float4*)&x[i];
        half4h h = { (_Float16)v.x, (_Float16)v.y, (_Float16)v.z, (_Float16)v.w };
        *(half4h*)&xh[i] = h;
    } else {
        int t = (b - (N_NODES * F_IN / 4) / 256) * 256 + threadIdx.x;
        if (t < F_IN * HID) {
            int r = t >> 8, c = t & 255;
            W1T[c * F_IN + r] = (_Float16)W1[t];
        } else if (t < F_IN * HID + HID * EMB) {
            int u = t - F_IN * HID;
            int r = u >> 6, c = u & 63;
            W2T[c * HID + r] = (_Float16)W2[u];
        }
    }
}

// ---------------- MFMA f16 GEMM: C[M,N] = Ah[M,K] @ BT[N,K]^T ----------------
// Wave: 16 rows x CT 16-col tiles, full K. Block = 4 waves = 64 rows.
// Both fragments are contiguous 16B row chunks; k-permutation cancels between operands;
// C/D layout is the m89/m91 HW-verified mapping.

template <int K, int N, int CT, bool OUT_HALF>
__global__ __launch_bounds__(256) void gemm_mfma(const _Float16* __restrict__ Ah,
                                                 const _Float16* __restrict__ BT,
                                                 _Float16* __restrict__ Ch,
                                                 float* __restrict__ Cf) {
    const int lane = threadIdx.x & 63;
    const int wave = threadIdx.x >> 6;
    const int row0 = blockIdx.y * 64 + wave * 16;
    const int col0 = blockIdx.x * (CT * 16);
    const int l16 = lane & 15;
    const int koff = (lane >> 4) * 8;

    floatx4 acc[CT];
#pragma unroll
    for (int ct = 0; ct < CT; ct++) acc[ct] = (floatx4){0.f, 0.f, 0.f, 0.f};

#pragma unroll
    for (int ks = 0; ks < K / 32; ks++) {
        half8 a = *(const half8*)&Ah[(size_t)(row0 + l16) * K + ks * 32 + koff];
#pragma unroll
        for (int ct = 0; ct < CT; ct++) {
            half8 b = *(const half8*)&BT[(size_t)(col0 + ct * 16 + l16) * K + ks * 32 + koff];
            acc[ct] = __builtin_amdgcn_mfma_f32_16x16x32_f16(a, b, acc[ct], 0, 0, 0);
        }
    }

    const int rb = (lane >> 4) * 4;
#pragma unroll
    for (int ct = 0; ct < CT; ct++)
#pragma unroll
        for (int r = 0; r < 4; r++) {
            size_t row = (size_t)(row0 + rb + r);
            int col = col0 + ct * 16 + l16;
            if constexpr (OUT_HALF) Ch[row * N + col] = (_Float16)acc[ct][r];
            else                    Cf[row * N + col] = acc[ct][r];
        }
}

// ---------------- SpMM layer 1: one node per wave, packed edges, unroll 4 ----------------

__global__ __launch_bounds__(256) void spmm_h(const _Float16* __restrict__ sup, const int* __restrict__ offs,
                                              const int2* __restrict__ epack, _Float16* __restrict__ outh) {
    const int lane = threadIdx.x & 63;
    const int node = __builtin_amdgcn_readfirstlane(blockIdx.x * 4 + (threadIdx.x >> 6));
    const int s = offs[node], e = offs[node + 1];
    floatx4 acc = {0.f, 0.f, 0.f, 0.f};
    int i = s;
    for (; i + 4 <= e; i += 4) {
        int2 e0 = epack[i], e1 = epack[i + 1], e2 = epack[i + 2], e3 = epack[i + 3];
        half4h v0 = *(const half4h*)&sup[(size_t)e0.x * HID + lane * 4];
        half4h v1 = *(const half4h*)&sup[(size_t)e1.x * HID + lane * 4];
        half4h v2 = *(const half4h*)&sup[(size_t)e2.x * HID + lane * 4];
        half4h v3 = *(const half4h*)&sup[(size_t)e3.x * HID + lane * 4];
        float w0 = __int_as_float(e0.y), w1 = __int_as_float(e1.y);
        float w2 = __int_as_float(e2.y), w3 = __int_as_float(e3.y);
        acc.x = fmaf(w0, (float)v0.x, acc.x); acc.y = fmaf(w0, (float)v0.y, acc.y);
        acc.z = fmaf(w0, (float)v0.z, acc.z); acc.w = fmaf(w0, (float)v0.w, acc.w);
        acc.x = fmaf(w1, (float)v1.x, acc.x); acc.y = fmaf(w1, (float)v1.y, acc.y);
        acc.z = fmaf(w1, (float)v1.z, acc.z); acc.w = fmaf(w1, (float)v1.w, acc.w);
        acc.x = fmaf(w2, (float)v2.x, acc.x); acc.y = fmaf(w2, (float)v2.y, acc.y);
        acc.z = fmaf(w2, (float)v2.z, acc.z); acc.w = fmaf(w2, (float)v2.w, acc.w);
        acc.x = fmaf(w3, (float)v3.x, acc.x); acc.y = fmaf(w3, (float)v3.y, acc.y);
        acc.z = fmaf(w3, (float)v3.z, acc.z); acc.w = fmaf(w3, (float)v3.w, acc.w);
    }
    for (; i < e; i++) {
        int2 e0 = epack[i];
        float w0 = __int_as_float(e0.y);
        half4h v0 = *(const half4h*)&sup[(size_t)e0.x * HID + lane * 4];
        acc.x = fmaf(w0, (float)v0.x, acc.x); acc.y = fmaf(w0, (float)v0.y, acc.y);
        acc.z = fmaf(w0, (float)v0.z, acc.z); acc.w = fmaf(w0, (float)v0.w, acc.w);
    }
    half4h o = { (_Float16)acc.x, (_Float16)acc.y, (_Float16)acc.z, (_Float16)acc.w };
    *(half4h*)&outh[(size_t)node * HID + lane * 4] = o;
}

// ---------------- SpMM layer 2 + L2-normalize: one node per wave, packed edges ----------------

__global__ __launch_bounds__(256) void spmm_norm(const float* __restrict__ sup, const int* __restrict__ offs,
                                                 const int2* __restrict__ epack,
                                                 float* __restrict__ z, _Float16* __restrict__ zh) {
    const int lane = threadIdx.x & 63;
    const int node = __builtin_amdgcn_readfirstlane(blockIdx.x * 4 + (threadIdx.x >> 6));
    const int s = offs[node], e = offs[node + 1];
    float acc = 0.f;
    int i = s;
    for (; i + 4 <= e; i += 4) {
        int2 e0 = epack[i], e1 = epack[i + 1], e2 = epack[i + 2], e3 = epack[i + 3];
        acc = fmaf(__int_as_float(e0.y), sup[(size_t)e0.x * EMB + lane], acc);
        acc = fmaf(__int_as_float(e1.y), sup[(size_t)e1.x * EMB + lane], acc);
        acc = fmaf(__int_as_float(e2.y), sup[(size_t)e2.x * EMB + lane], acc);
        acc = fmaf(__int_as_float(e3.y), sup[(size_t)e3.x * EMB + lane], acc);
    }
    for (; i < e; i++) {
        int2 e0 = epack[i];
        acc = fmaf(__int_as_float(e0.y), sup[(size_t)e0.x * EMB + lane], acc);
    }
    float sq = acc * acc;
#pragma unroll
    for (int m = 1; m < 64; m <<= 1) sq += __shfl_xor(sq, m);
    float inv = 1.f / fmaxf(sqrtf(sq), 1e-12f);
    acc *= inv;
    z[(size_t)node * EMB + lane] = acc;
    zh[(size_t)node * EMB + lane] = (_Float16)acc;
}

// ---------------- decode: A = sigmoid(zh @ zh^T) via f16 MFMA, no LDS (HW-verified r6) ----------------

__global__ __launch_bounds__(256) void k_decode(const _Float16* __restrict__ zh, float* __restrict__ A) {
    const int i0 = blockIdx.y * 128;
    const int j0 = blockIdx.x * 128;
    const int lane = threadIdx.x & 63;
    const int wave = threadIdx.x >> 6;
    const int l16 = lane & 15;
    const int koff = (lane >> 4) * 8;

    half8 a[2][2], b[8][2];
#pragma unroll
    for (int rt = 0; rt < 2; rt++)
#pragma unroll
        for (int s = 0; s < 2; s++)
            a[rt][s] = *(const half8*)&zh[(size_t)(i0 + wave * 32 + rt * 16 + l16) * EMB + s * 32 + koff];
#pragma unroll
    for (int ct = 0; ct < 8; ct++)
#pragma unroll
        for (int s = 0; s < 2; s++)
            b[ct][s] = *(const half8*)&zh[(size_t)(j0 + ct * 16 + l16) * EMB + s * 32 + koff];

    floatx4 acc[2][8];
#pragma unroll
    for (int rt = 0; rt < 2; rt++)
#pragma unroll
        for (int ct = 0; ct < 8; ct++)
            acc[rt][ct] = (floatx4){0.f, 0.f, 0.f, 0.f};

#pragma unroll
    for (int s = 0; s < 2; s++)
#pragma unroll
        for (int rt = 0; rt < 2; rt++)
#pragma unroll
            for (int ct = 0; ct < 8; ct++)
                acc[rt][ct] = __builtin_amdgcn_mfma_f32_16x16x32_f16(a[rt][s], b[ct][s], acc[rt][ct], 0, 0, 0);

    const int rbase = (lane >> 4) * 4;
#pragma unroll
    for (int rt = 0; rt < 2; rt++)
#pragma unroll
        for (int r = 0; r < 4; r++) {
            size_t row = (size_t)(i0 + wave * 32 + rt * 16 + rbase + r);
#pragma unroll
            for (int ct = 0; ct < 8; ct++) {
                float v = acc[rt][ct][r];
                A[row * N_NODES + j0 + ct * 16 + l16] = 1.f / (1.f + __expf(-v));
            }
        }
}

// ---------------- launch ----------------

extern "C" void kernel_launch(void* const* d_in, const int* in_sizes, int n_in,
                              void* d_out, int out_size, void* d_ws, size_t ws_size,
                              hipStream_t stream) {
    const float* x  = (const float*)d_in[0];
    const int*   ei = (const int*)d_in[1];     // [2, E]: src row then dst row
    const float* ew = (const float*)d_in[2];
    const float* W1 = (const float*)d_in[3];
    const float* W2 = (const float*)d_in[4];
    float* out = (float*)d_out;
    float* z   = out + (size_t)N_NODES * N_NODES;  // fp32 z output region

    _Float16* xh   = (_Float16*)d_ws;                  // 8 MB
    _Float16* W1T  = xh + (size_t)N_NODES * F_IN;      // 256 KB
    _Float16* W2T  = W1T + F_IN * HID;                 // 32 KB
    _Float16* s1h  = W2T + HID * EMB;                  // 4 MB  [8192][256]
    _Float16* h1h  = s1h + (size_t)N_NODES * HID;      // 4 MB  [8192][256]
    _Float16* zh   = h1h + (size_t)N_NODES * HID;      // 1 MB  [8192][64]
    float* s2      = (float*)(zh + (size_t)N_NODES * EMB);  // 2 MB [8192][64]
    int* offs      = (int*)(s2 + (size_t)N_NODES * EMB);    // 8448
    int* cnt       = offs + 8448;                      // 8192
    int2* epack    = (int2*)(cnt + 8192);              // 2 MB packed (dst, w)

    const int* src = ei;
    const int* dst = ei + NEDGE;

    // CSR build
    hipMemsetAsync(cnt, 0, N_NODES * sizeof(int), stream);
    k_count<<<NEDGE / 256, 256, 0, stream>>>(src, cnt);
    k_scan<<<1, 1024, 0, stream>>>(cnt, offs);
    k_fill<<<NEDGE / 256, 256, 0, stream>>>(src, dst, ew, cnt, epack);

    // converts (merged)
    k_cvt<<<(N_NODES * F_IN / 4) / 256 + (F_IN * HID + HID * EMB + 255) / 256, 256, 0, stream>>>(
        x, W1, W2, xh, W1T, W2T);

    // layer 1: MFMA GEMM (f16 out) + wave-uniform f16 SpMM
    gemm_mfma<F_IN, HID, 4, true><<<dim3(HID / 64, N_NODES / 64), 256, 0, stream>>>(xh, W1T, s1h, nullptr);
    spmm_h<<<N_NODES / 4, 256, 0, stream>>>(s1h, offs, epack, h1h);

    // layer 2: MFMA GEMM (f32 out) + wave-uniform SpMM fused with normalize
    gemm_mfma<HID, EMB, 4, false><<<dim3(EMB / 64, N_NODES / 64), 256, 0, stream>>>(h1h, W2T, nullptr, s2);
    spmm_norm<<<N_NODES / 4, 256, 0, stream>>>(s2, offs, epack, z, zh);

    // decode: dense 64x64 tile grid, MFMA, no LDS
    k_decode<<<dim3(N_NODES / 128, N_NODES / 128), 256, 0, stream>>>(zh, out);
}